// Round 1
// baseline (868.225 us; speedup 1.0000x reference)
//
#include <hip/hip_runtime.h>
#include <hip/hip_bf16.h>

typedef __bf16 bf16_t;
typedef bf16_t bf16x8 __attribute__((ext_vector_type(8)));
typedef bf16_t bf16x4 __attribute__((ext_vector_type(4)));
typedef float floatx4 __attribute__((ext_vector_type(4)));

#define B_  64
#define SQ  1024
#define SK  1024
#define D_  256
#define DV  256
#define TK  32
#define SCALE_F 0.0625f
#define KEEP_F  (1.0f/0.9f)
#define THRESH  0.1f

// One block = 4 waves = 64 Q rows. K-tiles of 32 keys, online softmax.
// LDS: Ks 32x264 bf16 (pad 8 -> 2-way-free b128 reads), Vt 256x40 (transposed V),
// Ps 64x40 (P C-layout -> A-layout round trip, wave-private rows).
__global__ __launch_bounds__(256, 3) void attn_fused(
    const float* __restrict__ q, const float* __restrict__ k,
    const float* __restrict__ v, const int* __restrict__ mask,
    const float* __restrict__ du, float* __restrict__ out)
{
    __shared__ bf16_t Ks[TK][264];
    __shared__ bf16_t Vt[DV][40];
    __shared__ bf16_t Ps[64][40];

    const int bid  = blockIdx.x;
    const int b    = bid >> 4;    // batch (b-major grid: blocks sharing b co-resident)
    const int qt   = bid & 15;    // q tile of 64 rows
    const int tid  = threadIdx.x;
    const int wave = tid >> 6;
    const int lane = tid & 63;
    const int col  = lane & 15;   // n / col within 16 (also A-frag row m)
    const int quad = lane >> 4;   // 0..3

    // ---- Q fragments in registers (A-layout: m=col, k=quad*8+j per 32-chunk) ----
    bf16x8 qf[8];
    {
        const float* qp = q + ((size_t)(b*SQ + qt*64 + wave*16 + col))*D_ + quad*8;
        #pragma unroll
        for (int c = 0; c < 8; ++c) {
            float4 a  = *(const float4*)(qp + c*32);
            float4 bb = *(const float4*)(qp + c*32 + 4);
            bf16x8 f;
            f[0]=(bf16_t)a.x;  f[1]=(bf16_t)a.y;  f[2]=(bf16_t)a.z;  f[3]=(bf16_t)a.w;
            f[4]=(bf16_t)bb.x; f[5]=(bf16_t)bb.y; f[6]=(bf16_t)bb.z; f[7]=(bf16_t)bb.w;
            qf[c] = f;
        }
    }

    floatx4 o_acc[16];
    #pragma unroll
    for (int i = 0; i < 16; ++i) o_acc[i] = (floatx4){0.f,0.f,0.f,0.f};
    float m_i[4] = {-1e30f,-1e30f,-1e30f,-1e30f};
    float l_i[4] = {0.f,0.f,0.f,0.f};

    const int r_st  = tid >> 3;   // staging row 0..31
    const int c8_st = tid & 7;    // staging 32-col group

    for (int kt = 0; kt < SK/TK; ++kt) {
        __syncthreads();  // all waves done reading previous tile's LDS
        // ---- stage K tile (row-major) and V tile (transposed) ----
        {
            const float* kp = k + ((size_t)(b*SK + kt*TK + r_st))*D_ + c8_st*32;
            const float* vp = v + ((size_t)(b*SK + kt*TK + r_st))*DV + c8_st*32;
            #pragma unroll
            for (int j = 0; j < 8; ++j) {
                float4 k4 = *(const float4*)(kp + j*4);
                bf16x4 kb;
                kb[0]=(bf16_t)k4.x; kb[1]=(bf16_t)k4.y; kb[2]=(bf16_t)k4.z; kb[3]=(bf16_t)k4.w;
                *(bf16x4*)(&Ks[r_st][c8_st*32 + j*4]) = kb;
                float4 v4 = *(const float4*)(vp + j*4);
                int dv = c8_st*32 + j*4;
                Vt[dv+0][r_st] = (bf16_t)v4.x;
                Vt[dv+1][r_st] = (bf16_t)v4.y;
                Vt[dv+2][r_st] = (bf16_t)v4.z;
                Vt[dv+3][r_st] = (bf16_t)v4.w;
            }
        }
        __syncthreads();

        // ---- S = Q K^T : 16 rows x 32 keys per wave ----
        floatx4 s0 = (floatx4){0,0,0,0}, s1 = (floatx4){0,0,0,0};
        #pragma unroll
        for (int c = 0; c < 8; ++c) {
            bf16x8 kf0 = *(bf16x8*)(&Ks[col     ][c*32 + quad*8]);
            bf16x8 kf1 = *(bf16x8*)(&Ks[col + 16][c*32 + quad*8]);
            s0 = __builtin_amdgcn_mfma_f32_16x16x32_bf16(qf[c], kf0, s0, 0,0,0);
            s1 = __builtin_amdgcn_mfma_f32_16x16x32_bf16(qf[c], kf1, s1, 0,0,0);
        }

        // ---- scale + additive mask, online softmax (rows = quad*4+i, cols = col+16*nb) ----
        const int kbase = kt*TK;
        const float mm0 = mask[b*SK + kbase + col]      ? 0.f : -1e9f;
        const float mm1 = mask[b*SK + kbase + 16 + col] ? 0.f : -1e9f;

        float sv0[4], sv1[4], alpha[4];
        #pragma unroll
        for (int i = 0; i < 4; ++i) {
            sv0[i] = s0[i]*SCALE_F + mm0;
            sv1[i] = s1[i]*SCALE_F + mm1;
            float mx = fmaxf(sv0[i], sv1[i]);
            #pragma unroll
            for (int off = 1; off < 16; off <<= 1) mx = fmaxf(mx, __shfl_xor(mx, off));
            float mnew = fmaxf(m_i[i], mx);
            alpha[i] = __expf(m_i[i] - mnew);
            m_i[i] = mnew;
        }

        // p (pre-dropout) feeds l; p*keep feeds PV (reference drops AFTER softmax).
        const float* dup = du + ((size_t)(b*SQ + qt*64 + wave*16 + quad*4))*SK + kbase + col;
        #pragma unroll
        for (int i = 0; i < 4; ++i) {
            float p0 = __expf(sv0[i] - m_i[i]);
            float p1 = __expf(sv1[i] - m_i[i]);
            float rs = p0 + p1;
            #pragma unroll
            for (int off = 1; off < 16; off <<= 1) rs += __shfl_xor(rs, off);
            l_i[i] = l_i[i]*alpha[i] + rs;
            float u0 = dup[(size_t)i*SK];
            float u1 = dup[(size_t)i*SK + 16];
            p0 *= (u0 >= THRESH) ? KEEP_F : 0.f;
            p1 *= (u1 >= THRESH) ? KEEP_F : 0.f;
            Ps[wave*16 + quad*4 + i][col]      = (bf16_t)p0;
            Ps[wave*16 + quad*4 + i][col + 16] = (bf16_t)p1;
        }

        // rescale O by alpha (per C-layout row i)
        floatx4 av = {alpha[0], alpha[1], alpha[2], alpha[3]};
        #pragma unroll
        for (int blk = 0; blk < 16; ++blk) o_acc[blk] *= av;

        // ---- O += P V  (Ps rows are wave-private; in-wave LDS RAW handled by lgkmcnt) ----
        bf16x8 pf = *(bf16x8*)(&Ps[wave*16 + col][quad*8]);
        #pragma unroll
        for (int blk = 0; blk < 16; ++blk) {
            bf16x8 vf = *(bf16x8*)(&Vt[blk*16 + col][quad*8]);
            o_acc[blk] = __builtin_amdgcn_mfma_f32_16x16x32_bf16(pf, vf, o_acc[blk], 0,0,0);
        }
    }

    // ---- epilogue: normalize by l, store fp32 ----
    float inv_l[4];
    #pragma unroll
    for (int i = 0; i < 4; ++i) inv_l[i] = 1.f/l_i[i];
    float* op = out + ((size_t)(b*SQ + qt*64 + wave*16 + quad*4))*DV + col;
    #pragma unroll
    for (int blk = 0; blk < 16; ++blk) {
        #pragma unroll
        for (int i = 0; i < 4; ++i)
            op[(size_t)i*DV + blk*16] = o_acc[blk][i]*inv_l[i];
    }
}

extern "C" void kernel_launch(void* const* d_in, const int* in_sizes, int n_in,
                              void* d_out, int out_size, void* d_ws, size_t ws_size,
                              hipStream_t stream) {
    const float* q    = (const float*)d_in[0];
    const float* k    = (const float*)d_in[1];
    const float* v    = (const float*)d_in[2];
    const int*   mask = (const int*)d_in[3];
    const float* du   = (const float*)d_in[4];
    float* out = (float*)d_out;
    dim3 grid(B_ * (SQ/64)), block(256);
    hipLaunchKernelGGL(attn_fused, grid, block, 0, stream, q, k, v, mask, du, out);
}

// Round 2
// 663.447 us; speedup vs baseline: 1.3087x; 1.3087x over previous
//
#include <hip/hip_runtime.h>
#include <hip/hip_bf16.h>
#include <stdint.h>

typedef __bf16 bf16_t;
typedef bf16_t bf16x8 __attribute__((ext_vector_type(8)));
typedef bf16_t bf16x4 __attribute__((ext_vector_type(4)));
typedef float floatx4 __attribute__((ext_vector_type(4)));

#define B_  64
#define SQ  1024
#define SK  1024
#define D_  256
#define DV  256
#define TK  32
#define NT  32
#define SCALE_F 0.0625f
#define NMASK   (-1.0e9f)
#define KEEP_F  (1.0f/0.9f)
#define THRESH  0.1f

#define AS1(p) ((const __attribute__((address_space(1))) uint32_t*)(p))
#define AS3(p) ((__attribute__((address_space(3))) uint32_t*)(p))

#define RAW_BARRIER() __asm__ volatile("s_barrier" ::: "memory")
#define WAIT_VM(N)    __asm__ volatile("s_waitcnt vmcnt(" #N ")" ::: "memory")
#define WAIT_LGKM0()  __asm__ volatile("s_waitcnt lgkmcnt(0)" ::: "memory")

__device__ __forceinline__ void gload16(const void* g, void* lds) {
    // async global->LDS, 16B/lane; LDS base is wave-uniform, HW adds lane*16
    __builtin_amdgcn_global_load_lds(AS1(g), AS3(lds), 16, 0, 0);
}

template<int CTRL>
__device__ __forceinline__ float dpp_f(float x) {
    int y = __builtin_amdgcn_update_dpp(0, __float_as_int(x), CTRL, 0xF, 0xF, true);
    return __int_as_float(y);
}
// reductions over 16 contiguous lanes (one DPP "row") — VALU pipe, no LDS
__device__ __forceinline__ float rowsum16(float v) {
    v += dpp_f<0x128>(v);   // row_ror:8
    v += dpp_f<0x124>(v);   // row_ror:4
    v += dpp_f<0x4E>(v);    // quad_perm(2,3,0,1)
    v += dpp_f<0xB1>(v);    // quad_perm(1,0,3,2)
    return v;
}
__device__ __forceinline__ float rowmax16(float v) {
    v = fmaxf(v, dpp_f<0x128>(v));
    v = fmaxf(v, dpp_f<0x124>(v));
    v = fmaxf(v, dpp_f<0x4E>(v));
    v = fmaxf(v, dpp_f<0xB1>(v));
    return v;
}

// ---------------- pre-pass: K,V fp32 -> bf16 tiles, swizzled for LDS DMA ----------------
// K tile (b,kt): 32 rows x 256 d. elem (r,d): offset r*512 + ((d>>3)^(r&7))*16 + (d&7)*2
// V tile (b,kt): 256 dv x 32 kk (transposed). elem (dv,kk): dv*64 + (((kk>>3)^((dv>>1)&3))*16) + (kk&7)*2
__global__ __launch_bounds__(256) void prepass(
    const float* __restrict__ k, const float* __restrict__ v,
    bf16_t* __restrict__ ktiles, bf16_t* __restrict__ vtiles)
{
    __shared__ bf16_t Vls[32 * 258];   // padded transpose staging
    const int bid = blockIdx.x;
    const int tid = threadIdx.x;
    if (bid < 2048) {
        const int r = tid >> 3;
        const float* src = k + ((size_t)(bid * 32 + r)) * D_ + (tid & 7) * 32;
        char* dst = (char*)ktiles + ((size_t)bid) * 16384;
        #pragma unroll
        for (int gl = 0; gl < 4; ++gl) {
            float4 a = *(const float4*)(src + gl * 8);
            float4 b4 = *(const float4*)(src + gl * 8 + 4);
            bf16x8 f;
            f[0]=(bf16_t)a.x;  f[1]=(bf16_t)a.y;  f[2]=(bf16_t)a.z;  f[3]=(bf16_t)a.w;
            f[4]=(bf16_t)b4.x; f[5]=(bf16_t)b4.y; f[6]=(bf16_t)b4.z; f[7]=(bf16_t)b4.w;
            int g = (tid & 7) * 4 + gl;
            *(bf16x8*)(dst + r * 512 + ((g ^ (r & 7)) * 16)) = f;
        }
    } else {
        const int bid2 = bid - 2048;
        const int kk = tid >> 3, dv0 = (tid & 7) * 32;
        const float* src = v + ((size_t)(bid2 * 32 + kk)) * DV + dv0;
        #pragma unroll
        for (int j = 0; j < 8; ++j) {
            float4 a = *(const float4*)(src + j * 4);
            bf16x4 f4;
            f4[0]=(bf16_t)a.x; f4[1]=(bf16_t)a.y; f4[2]=(bf16_t)a.z; f4[3]=(bf16_t)a.w;
            *(bf16x4*)(&Vls[kk * 258 + dv0 + j * 4]) = f4;
        }
        __syncthreads();
        char* dst = (char*)vtiles + ((size_t)bid2) * 16384;
        #pragma unroll
        for (int c = 0; c < 4; ++c) {
            int dv = c * 64 + (tid >> 2);
            int gphys = tid & 3;
            int glog = gphys ^ ((dv >> 1) & 3);
            bf16x8 f;
            #pragma unroll
            for (int jj = 0; jj < 8; ++jj) f[jj] = Vls[(glog * 8 + jj) * 258 + dv];
            *(bf16x8*)(dst + dv * 64 + gphys * 16) = f;
        }
    }
}

// ---------------- main fused attention ----------------
// LDS: Ks 16KB @0 | Vt 16KB @16384 | Dus 2x8KB @32768 | Ps 4KB @49152  = 52KB -> 3 blocks/CU
__global__ __launch_bounds__(256, 3) void attn_main(
    const float* __restrict__ q, const int* __restrict__ mask,
    const float* __restrict__ du, const bf16_t* __restrict__ ktiles,
    const bf16_t* __restrict__ vtiles, float* __restrict__ out)
{
    __shared__ char smem[53248];
    char* KsB = smem;
    char* VtB = smem + 16384;
    char* DuB = smem + 32768;
    char* PsB = smem + 49152;

    const int bid  = blockIdx.x;
    const int b    = bid >> 4;
    const int qt   = bid & 15;
    const int tid  = threadIdx.x;
    const int wave = tid >> 6;
    const int lane = tid & 63;
    const int col  = lane & 15;
    const int quad = lane >> 4;

    // Q fragments (A-layout), SCALE folded in before bf16 cvt
    bf16x8 qf[8];
    {
        const float* qp = q + ((size_t)(b*SQ + qt*64 + wave*16 + col))*D_ + quad*8;
        #pragma unroll
        for (int c = 0; c < 8; ++c) {
            float4 a  = *(const float4*)(qp + c*32);
            float4 b4 = *(const float4*)(qp + c*32 + 4);
            bf16x8 f;
            f[0]=(bf16_t)(a.x*SCALE_F);  f[1]=(bf16_t)(a.y*SCALE_F);
            f[2]=(bf16_t)(a.z*SCALE_F);  f[3]=(bf16_t)(a.w*SCALE_F);
            f[4]=(bf16_t)(b4.x*SCALE_F); f[5]=(bf16_t)(b4.y*SCALE_F);
            f[6]=(bf16_t)(b4.z*SCALE_F); f[7]=(bf16_t)(b4.w*SCALE_F);
            qf[c] = f;
        }
    }

    floatx4 o_acc[16];
    #pragma unroll
    for (int i = 0; i < 16; ++i) o_acc[i] = (floatx4){0.f,0.f,0.f,0.f};
    float m_i[4] = {-1e30f,-1e30f,-1e30f,-1e30f};
    float l_i[4] = {0.f,0.f,0.f,0.f};

    const size_t tbase = (size_t)(b * NT) * 16384;

    // --- staging issue helpers (4 waves share each tile; 4/4/2 instrs per wave) ---
    #define ISSUE_K(t) do { \
        const char* g_ = (const char*)ktiles + tbase + (size_t)(t)*16384 + wave*4096 + lane*16; \
        char* l_ = KsB + wave*4096; \
        gload16(g_, l_); gload16(g_+1024, l_+1024); \
        gload16(g_+2048, l_+2048); gload16(g_+3072, l_+3072); } while(0)

    #define ISSUE_V(t) do { \
        const char* g_ = (const char*)vtiles + tbase + (size_t)(t)*16384 + wave*4096 + lane*16; \
        char* l_ = VtB + wave*4096; \
        gload16(g_, l_); gload16(g_+1024, l_+1024); \
        gload16(g_+2048, l_+2048); gload16(g_+3072, l_+3072); } while(0)

    #define ISSUE_DU(t, buf) do { \
        char* l_ = DuB + (buf)*8192 + wave*2048; \
        _Pragma("unroll") \
        for (int s_ = 0; s_ < 2; ++s_) { \
            int row_ = wave*16 + s_*8 + (lane>>3); \
            int cl_ = (lane & 7) ^ (row_ & 7); \
            const char* g_ = (const char*)du + \
                (((size_t)(b*SQ + qt*64 + row_))*SK + (t)*TK + cl_*4)*4; \
            gload16(g_, l_ + s_*1024); \
        } } while(0)

    // preamble: tile 0 in flight  (order: Ks, du, mask, Vt)
    ISSUE_K(0);
    ISSUE_DU(0, 0);
    int mcur0 = mask[b*SK + col];
    int mcur1 = mask[b*SK + 16 + col];
    ISSUE_V(0);

    for (int kt = 0; kt < NT; ++kt) {
        const int tn = (kt + 1 < NT) ? kt + 1 : NT - 1;   // clamp -> constant vmcnt counts

        WAIT_VM(4);          // Ks[kt], du[kt], mask landed; Vt[kt] still in flight
        RAW_BARRIER();       // #1: staged data visible to all waves

        // du[kt+1] + mask[kt+1]: issue now (other buffer / regs) -> full iter to land
        ISSUE_DU(tn, (kt + 1) & 1);
        int mn0 = mask[b*SK + tn*TK + col];
        int mn1 = mask[b*SK + tn*TK + 16 + col];

        // ---- S = Q K^T ----
        floatx4 s0 = (floatx4){0,0,0,0}, s1 = (floatx4){0,0,0,0};
        #pragma unroll
        for (int c = 0; c < 8; ++c) {
            const int g0 = c*4 + quad;
            const int r0 = col, r1 = col + 16;
            bf16x8 kf0 = *(const bf16x8*)(KsB + r0*512 + ((g0 ^ (r0 & 7)) * 16));
            bf16x8 kf1 = *(const bf16x8*)(KsB + r1*512 + ((g0 ^ (r1 & 7)) * 16));
            s0 = __builtin_amdgcn_mfma_f32_16x16x32_bf16(qf[c], kf0, s0, 0,0,0);
            s1 = __builtin_amdgcn_mfma_f32_16x16x32_bf16(qf[c], kf1, s1, 0,0,0);
        }

        // ---- online softmax + dropout + Ps write ----
        const float mm0 = mcur0 ? 0.f : NMASK;
        const float mm1 = mcur1 ? 0.f : NMASK;
        const char* duB = DuB + (kt & 1) * 8192;
        float alpha[4];
        #pragma unroll
        for (int i = 0; i < 4; ++i) {
            float sv0 = s0[i] + mm0;
            float sv1 = s1[i] + mm1;
            float mx = rowmax16(fmaxf(sv0, sv1));
            float mnew = fmaxf(m_i[i], mx);
            alpha[i] = __expf(m_i[i] - mnew);
            m_i[i] = mnew;
            float p0 = __expf(sv0 - mnew);
            float p1 = __expf(sv1 - mnew);
            float rs = rowsum16(p0 + p1);
            l_i[i] = l_i[i] * alpha[i] + rs;

            const int row = wave*16 + quad*4 + i;
            const int k0 = col, k1 = col + 16;
            float u0 = *(const float*)(duB + row*128 + (((k0>>2) ^ (row & 7)) * 16) + (k0 & 3)*4);
            float u1 = *(const float*)(duB + row*128 + (((k1>>2) ^ (row & 7)) * 16) + (k1 & 3)*4);
            p0 *= (u0 >= THRESH) ? KEEP_F : 0.f;
            p1 *= (u1 >= THRESH) ? KEEP_F : 0.f;
            *(bf16_t*)(PsB + row*64 + (((k0>>3) ^ ((row>>1) & 3)) * 16) + (k0 & 7)*2) = (bf16_t)p0;
            *(bf16_t*)(PsB + row*64 + (((k1>>3) ^ ((row>>1) & 3)) * 16) + (k1 & 7)*2) = (bf16_t)p1;
        }
        {
            floatx4 av = {alpha[0], alpha[1], alpha[2], alpha[3]};
            #pragma unroll
            for (int blk = 0; blk < 16; ++blk) o_acc[blk] *= av;
        }

        WAIT_LGKM0();
        RAW_BARRIER();       // #2: all waves done reading Ks[kt] -> region free
        ISSUE_K(tn);         // Ks[kt+1] in flight across PV phase

        WAIT_VM(8);          // drain Vt[kt] (leave Ks[kt+1]+du[kt+1]+... in flight)
        RAW_BARRIER();       // #3: Vt[kt] visible to all waves

        // ---- O += P V ----
        {
            const int prow = wave*16 + col;
            bf16x8 pf = *(const bf16x8*)(PsB + prow*64 + ((quad ^ ((prow>>1) & 3)) * 16));
            #pragma unroll
            for (int blk = 0; blk < 16; ++blk) {
                const int dv = blk*16 + col;
                bf16x8 vf = *(const bf16x8*)(VtB + dv*64 + ((quad ^ ((dv>>1) & 3)) * 16));
                o_acc[blk] = __builtin_amdgcn_mfma_f32_16x16x32_bf16(pf, vf, o_acc[blk], 0,0,0);
            }
        }

        WAIT_LGKM0();
        RAW_BARRIER();       // #4: all waves done reading Vt[kt] -> region free
        ISSUE_V(tn);         // Vt[kt+1] in flight across next S+softmax

        mcur0 = mn0; mcur1 = mn1;
    }
    WAIT_VM(0);              // drain trailing redundant prefetches before LDS dealloc

    // ---- epilogue ----
    float inv_l[4];
    #pragma unroll
    for (int i = 0; i < 4; ++i) inv_l[i] = 1.f / l_i[i];
    float* op = out + ((size_t)(b*SQ + qt*64 + wave*16 + quad*4))*DV + col;
    #pragma unroll
    for (int blk = 0; blk < 16; ++blk) {
        #pragma unroll
        for (int i = 0; i < 4; ++i)
            op[(size_t)i*DV + blk*16] = o_acc[blk][i] * inv_l[i];
    }
    #undef ISSUE_K
    #undef ISSUE_V
    #undef ISSUE_DU
}

extern "C" void kernel_launch(void* const* d_in, const int* in_sizes, int n_in,
                              void* d_out, int out_size, void* d_ws, size_t ws_size,
                              hipStream_t stream) {
    const float* q    = (const float*)d_in[0];
    const float* k    = (const float*)d_in[1];
    const float* v    = (const float*)d_in[2];
    const int*   mask = (const int*)d_in[3];
    const float* du   = (const float*)d_in[4];
    float* out = (float*)d_out;

    bf16_t* ktiles = (bf16_t*)d_ws;                              // 32 MB
    bf16_t* vtiles = (bf16_t*)((char*)d_ws + (size_t)33554432);  // 32 MB

    hipLaunchKernelGGL(prepass, dim3(4096), dim3(256), 0, stream, k, v, ktiles, vtiles);
    hipLaunchKernelGGL(attn_main, dim3(B_ * (SQ/64)), dim3(256), 0, stream,
                       q, mask, du, ktiles, vtiles, out);
}